// Round 6
// baseline (308.287 us; speedup 1.0000x reference)
//
#include <hip/hip_runtime.h>
#include <stdint.h>

#define NB 4
#define NT 2048
#define ND 1024
#define NH 16
#define NDK 64
#define NTD 3072   // 3*ND

typedef __attribute__((ext_vector_type(8))) short short8;
typedef __attribute__((ext_vector_type(4))) float f32x4;
typedef unsigned short u16;
typedef unsigned int u32;

__device__ __forceinline__ u16 f2bf(float f) {
    u32 u = __builtin_bit_cast(u32, f);
    u += 0x7fffu + ((u >> 16) & 1u);   // RNE
    return (u16)(u >> 16);
}
__device__ __forceinline__ float bf2f(u16 s) {
    u32 u = ((u32)s) << 16;
    return __builtin_bit_cast(float, u);
}

__device__ __forceinline__ void gl_lds16(const u16* g, u16* l) {
    __builtin_amdgcn_global_load_lds(
        (const __attribute__((address_space(1))) u32*)g,
        (__attribute__((address_space(3))) u32*)l, 16, 0, 0);
}

// XOR-swizzled tile index (rows of 32 u16 / 64B, 4 atoms of 8 u16) - P tile.
__device__ __forceinline__ int swz(int row, int col) {
    return row * 32 + ((((col >> 3) ^ (row >> 1) ^ (row >> 3)) & 3) << 3) + (col & 7);
}

// ---------------- fused fp32 -> bf16 (RNE) for x, W_qkv, W_o ----------------
__global__ __launch_bounds__(256) void cvt_all(const float* __restrict__ x,
                                               const float* __restrict__ wqkv,
                                               const float* __restrict__ wo,
                                               u16* __restrict__ xb,
                                               u16* __restrict__ wqb,
                                               u16* __restrict__ wob) {
    const int n0 = NB * NT * ND;       // 8388608
    const int n1 = 3 * ND * ND;        // 3145728
    int i = (blockIdx.x * 256 + threadIdx.x) * 8;
    const float* src;
    u16* dst;
    if (i < n0) {
        src = x + i; dst = xb + i;
    } else if (i < n0 + n1) {
        src = wqkv + (i - n0); dst = wqb + (i - n0);
    } else {
        src = wo + (i - n0 - n1); dst = wob + (i - n0 - n1);
    }
    float4 a = *(const float4*)(src);
    float4 b = *(const float4*)(src + 4);
    short8 r;
    r[0] = (short)f2bf(a.x); r[1] = (short)f2bf(a.y);
    r[2] = (short)f2bf(a.z); r[3] = (short)f2bf(a.w);
    r[4] = (short)f2bf(b.x); r[5] = (short)f2bf(b.y);
    r[6] = (short)f2bf(b.z); r[7] = (short)f2bf(b.w);
    *(short8*)(dst) = r;
}

// ---------------- bf16 GEMM: C[M,N] = A[M,K] * Bm[N,K]^T ----------------
template <typename OutT>
__global__ __launch_bounds__(256) void gemm_bt(const u16* __restrict__ A,
                                               const u16* __restrict__ Bm,
                                               OutT* __restrict__ C,
                                               int M, int N, int K) {
    __shared__ __align__(16) u16 As[128 * 32];
    __shared__ __align__(16) u16 Bs[128 * 32];
    const int tid  = threadIdx.x;
    const int wave = tid >> 6, lane = tid & 63;
    const int quad = lane >> 4, l16 = lane & 15;
    const int wm = wave >> 1, wn = wave & 1;
    const int row0 = blockIdx.x * 128, col0 = blockIdx.y * 128;

    f32x4 acc[4][4];
#pragma unroll
    for (int i = 0; i < 4; ++i)
#pragma unroll
        for (int j = 0; j < 4; ++j) acc[i][j] = (f32x4){0.f, 0.f, 0.f, 0.f};

    const u16* Ag = A + (size_t)(row0 + (tid >> 2)) * K + ((tid & 3) * 8);
    const u16* Bg = Bm + (size_t)(col0 + (tid >> 2)) * K + ((tid & 3) * 8);
    const size_t stride64 = (size_t)64 * K;
    u16* As0 = As + wave * 512;
    u16* As1 = As + 2048 + wave * 512;
    u16* Bs0 = Bs + wave * 512;
    u16* Bs1 = Bs + 2048 + wave * 512;

    for (int k0 = 0; k0 < K; k0 += 32) {
        gl_lds16(Ag + k0, As0);
        gl_lds16(Ag + k0 + stride64, As1);
        gl_lds16(Bg + k0, Bs0);
        gl_lds16(Bg + k0 + stride64, Bs1);
        __syncthreads();
        short8 af[4], bfr[4];
#pragma unroll
        for (int mi = 0; mi < 4; ++mi)
            af[mi] = *(const short8*)&As[(wm * 64 + mi * 16 + l16) * 32 + quad * 8];
#pragma unroll
        for (int ni = 0; ni < 4; ++ni)
            bfr[ni] = *(const short8*)&Bs[(wn * 64 + ni * 16 + l16) * 32 + quad * 8];
#pragma unroll
        for (int mi = 0; mi < 4; ++mi)
#pragma unroll
            for (int ni = 0; ni < 4; ++ni)
                acc[mi][ni] = __builtin_amdgcn_mfma_f32_16x16x32_bf16(
                    af[mi], bfr[ni], acc[mi][ni], 0, 0, 0);
        __syncthreads();
    }

#pragma unroll
    for (int mi = 0; mi < 4; ++mi) {
#pragma unroll
        for (int ni = 0; ni < 4; ++ni) {
            const int r = row0 + wm * 64 + mi * 16 + quad * 4;
            const int c = col0 + wn * 64 + ni * 16 + l16;
#pragma unroll
            for (int rr = 0; rr < 4; ++rr) {
                float v = acc[mi][ni][rr];
                if constexpr (sizeof(OutT) == 2)
                    C[(size_t)(r + rr) * N + c] = (OutT)f2bf(v);
                else
                    C[(size_t)(r + rr) * N + c] = (OutT)v;
            }
        }
    }
}

// ---------------- V transpose: qkv V-section -> Vt[bh][d][t] ----------------
__global__ __launch_bounds__(256) void transpose_v(const u16* __restrict__ qkv,
                                                   u16* __restrict__ vt) {
    __shared__ __align__(16) u16 L[64 * 72];
    const int tid = threadIdx.x;
    const int bh = blockIdx.x, b = bh >> 4, h = bh & 15;
    const int t0 = blockIdx.y * 64;
    const u16* Vg = qkv + ((size_t)(b * NT + t0)) * NTD + 2 * ND + h * NDK;

    const int trow = tid >> 3, g = tid & 7;
#pragma unroll
    for (int rep = 0; rep < 2; ++rep) {
        const int t = trow + rep * 32;
        short8 v = *(const short8*)(Vg + (size_t)t * NTD + g * 8);
        *(short8*)&L[t * 72 + ((g ^ (t & 7)) << 3)] = v;
    }
    __syncthreads();
    const int d = tid & 63, w = tid >> 6;
    u16* O = vt + ((size_t)bh * 64 + d) * NT + t0;
#pragma unroll
    for (int rep = 0; rep < 2; ++rep) {
        const int c = w + rep * 4;
        short8 o;
#pragma unroll
        for (int j = 0; j < 8; ++j) {
            const int t = c * 8 + j;
            o[j] = L[t * 72 + ((((d >> 3) ^ (t & 7)) << 3)) + (d & 7)];
        }
        *(short8*)(O + c * 8) = o;
    }
}

// ---------------- flash prefix-LM attention (v6) ----------------
// grid (64 bh, 64 q-tiles of 32 rows), longest-first (q0=(63-y)*32).
// 4 waves: rowgrp = wave&1 (rows 0-15 / 16-31), pair = wave>>1 splits the
// staged 64-key tile (kcols 0-31 / 32-63). Constant-max exp2 softmax ->
// wave-pair partials (o,l) combine by plain addition through LDS.
// K/V double-buffered DMA, one barrier per 64 keys.
__global__ __launch_bounds__(256) void flash_prefix(const u16* __restrict__ qkv,
                                                    const u16* __restrict__ vt,
                                                    const int* __restrict__ plen,
                                                    u16* __restrict__ attn) {
    __shared__ __align__(16) u16 Kt2[2][4096];  // [k 64][d 64] swizzled chunks
    __shared__ __align__(16) u16 Vt2[2][4096];  // [d 64][t 64] swizzled chunks
    __shared__ __align__(16) u16 Pl[4 * 512];   // per-wave 16x32 swizzled

    const int tid  = threadIdx.x;
    const int wave = tid >> 6, lane = tid & 63;
    const int quad = lane >> 4, l16 = lane & 15;
    const int pair = wave >> 1, rg = wave & 1;
    const int bh = blockIdx.x, b = bh >> 4, h = bh & 15;
    const int q0 = (63 - blockIdx.y) * 32;      // longest blocks dispatched first

    int P;
    {
        bool is64 = (plen[1] == 0) && (plen[3] == 0);
        P = is64 ? plen[2 * b] : plen[b];
        P = P < 0 ? 0 : (P > NT ? NT : P);
    }

    const u16* Qg = qkv + (size_t)b * NT * NTD + h * NDK;
    const u16* Kg = Qg + ND;
    const u16* Vtb = vt + (size_t)bh * 64 * NT;   // [d][t]

    const int qbase = q0 + rg * 16;
    u16* Pw = Pl + wave * 512;
    const float QSCALE = 0.18033688f;      // log2(e)/8

    // DMA lane->source mapping (swizzle baked into global address).
    // K tile: atom a (16B): row k = a>>3, chunk slot a&7 holds source chunk (a^k)&7.
    const int krow = tid >> 3, kch = (tid ^ krow) & 7;
    const u16* ksp = Kg + (size_t)krow * NTD + kch * 8;       // atom i=0; i=1 adds 32*NTD
    // V tile: atom a: row d = a>>3, chunk slot a&7 holds source t-chunk (a^d)&7.
    const int vd = tid >> 3, vch = (tid ^ vd) & 7;
    const u16* vsp = Vtb + (size_t)vd * NT + vch * 8;         // i=1 adds 32*NT
    const int koff = wave * 512;  // per-wave u16 offset inside each 2048-u16 half

    // Q fragments pre-scaled into exp2 domain
    short8 qa[2];
#pragma unroll
    for (int kd = 0; kd < 2; ++kd) {
        short8 tq = *(const short8*)(Qg + (size_t)(qbase + l16) * NTD + kd * 32 + quad * 8);
#pragma unroll
        for (int j = 0; j < 8; ++j)
            tq[j] = (short)f2bf(bf2f((u16)tq[j]) * QSCALE);
        qa[kd] = tq;
    }

    short8 ones;
#pragma unroll
    for (int j = 0; j < 8; ++j) ones[j] = (short)0x3F80;

    f32x4 o[4];
#pragma unroll
    for (int nt = 0; nt < 4; ++nt) o[nt] = (f32x4){0.f, 0.f, 0.f, 0.f};
    f32x4 lsum = (f32x4){0.f, 0.f, 0.f, 0.f};

    int kl[4];
#pragma unroll
    for (int rr = 0; rr < 4; ++rr) {
        const int qrow = qbase + quad * 4 + rr;
        kl[rr] = (qrow < P) ? P : (qrow + 1);
    }
    const int klmin = (qbase < P) ? P : (qbase + 1);   // wave-uniform
    const int kmax = (q0 + 32 > P) ? (q0 + 32) : P;    // block-uniform

    // prefetch tile 0
    gl_lds16(ksp, &Kt2[0][koff]);
    gl_lds16(ksp + (size_t)32 * NTD, &Kt2[0][2048 + koff]);
    gl_lds16(vsp, &Vt2[0][koff]);
    gl_lds16(vsp + (size_t)32 * NT, &Vt2[0][2048 + koff]);
    const u16* ksn = ksp + (size_t)64 * NTD;
    const u16* vsn = vsp + 64;
    int buf = 0;

    for (int k0 = 0; k0 < kmax; k0 += 64) {
        __syncthreads();   // drains this wave's DMA for buf; all done reading buf^1
        if (k0 + 64 < kmax) {
            gl_lds16(ksn, &Kt2[buf ^ 1][koff]);
            gl_lds16(ksn + (size_t)32 * NTD, &Kt2[buf ^ 1][2048 + koff]);
            gl_lds16(vsn, &Vt2[buf ^ 1][koff]);
            gl_lds16(vsn + (size_t)32 * NT, &Vt2[buf ^ 1][2048 + koff]);
            ksn += (size_t)64 * NTD;
            vsn += 64;
        }
        const u16* Kb = Kt2[buf];
        const u16* Vb = Vt2[buf];

        // S = Q K^T for this wave's 32 kcols
        f32x4 s[2];
#pragma unroll
        for (int ni = 0; ni < 2; ++ni) {
            s[ni] = (f32x4){0.f, 0.f, 0.f, 0.f};
            const int r = pair * 32 + ni * 16 + l16;
#pragma unroll
            for (int kd = 0; kd < 2; ++kd) {
                const short8 kb = *(const short8*)&Kb[r * 64 + ((((kd * 4 + quad) ^ (l16 & 7)) & 7) << 3)];
                s[ni] = __builtin_amdgcn_mfma_f32_16x16x32_bf16(qa[kd], kb, s[ni], 0, 0, 0);
            }
        }

        // p = 2^s -> bf16 P tile in per-wave LDS
        const bool full = (k0 + pair * 32 + 32 <= klmin);   // wave-uniform
#pragma unroll
        for (int ni = 0; ni < 2; ++ni) {
#pragma unroll
            for (int rr = 0; rr < 4; ++rr) {
                float sv = s[ni][rr];
                if (!full) {
                    const int kpos = k0 + pair * 32 + ni * 16 + l16;
                    sv = (kpos < kl[rr]) ? sv : -1e30f;
                }
                const float p = exp2f(sv);
                const u32 u = __builtin_bit_cast(u32, p) + 0x8000u;
                Pw[swz(quad * 4 + rr, ni * 16 + l16)] = (u16)(u >> 16);
            }
        }

        // PV + row-sum over this wave's 32 kcols
        const short8 pa = *(const short8*)&Pw[swz(l16, quad * 8)];
        lsum = __builtin_amdgcn_mfma_f32_16x16x32_bf16(pa, ones, lsum, 0, 0, 0);
#pragma unroll
        for (int nt = 0; nt < 4; ++nt) {
            const int d = nt * 16 + l16;
            const short8 vb = *(const short8*)&Vb[d * 64 + ((((pair * 4 + quad) ^ (l16 & 7)) & 7) << 3)];
            o[nt] = __builtin_amdgcn_mfma_f32_16x16x32_bf16(pa, vb, o[nt], 0, 0, 0);
        }
        buf ^= 1;
    }

    // combine wave pairs (plain sums - constant-max softmax) via LDS aliased
    // onto the dead K tile (2*1056 f32 = 8.4 KB <= 16 KB).
    __syncthreads();
    float* comb = (float*)&Kt2[0][0];
    if (wave >= 2) {
        float* cw = comb + (wave - 2) * 1056;
#pragma unroll
        for (int nt = 0; nt < 4; ++nt)
#pragma unroll
            for (int rr = 0; rr < 4; ++rr)
                cw[(quad * 4 + rr) * 65 + nt * 16 + l16] = o[nt][rr];
        if (l16 == 0) {
#pragma unroll
            for (int rr = 0; rr < 4; ++rr)
                cw[1040 + quad * 4 + rr] = lsum[rr];
        }
    }
    __syncthreads();
    if (wave < 2) {
        const float* cw = comb + wave * 1056;
#pragma unroll
        for (int rr = 0; rr < 4; ++rr)
            lsum[rr] += cw[1040 + quad * 4 + rr];
#pragma unroll
        for (int nt = 0; nt < 4; ++nt)
#pragma unroll
            for (int rr = 0; rr < 4; ++rr)
                o[nt][rr] += cw[(quad * 4 + rr) * 65 + nt * 16 + l16];
#pragma unroll
        for (int rr = 0; rr < 4; ++rr) {
            const float inv = 1.0f / lsum[rr];
            const size_t rowoff = (size_t)(b * NT + qbase + quad * 4 + rr) * ND + h * NDK;
#pragma unroll
            for (int nt = 0; nt < 4; ++nt)
                attn[rowoff + nt * 16 + l16] = f2bf(o[nt][rr] * inv);
        }
    }
}

extern "C" void kernel_launch(void* const* d_in, const int* in_sizes, int n_in,
                              void* d_out, int out_size, void* d_ws, size_t ws_size,
                              hipStream_t stream) {
    const float* x    = (const float*)d_in[0];
    const int*   plen = (const int*)d_in[1];
    const float* wqkv = (const float*)d_in[2];
    const float* wo   = (const float*)d_in[3];
    float* out = (float*)d_out;

    char* ws = (char*)d_ws;
    u16* xb   = (u16*)(ws);                  // 16,777,216
    u16* wqb  = (u16*)(ws + 16777216);       //  6,291,456
    u16* wob  = (u16*)(ws + 23068672);       //  2,097,152
    u16* qkv  = (u16*)(ws + 25165824);       // 50,331,648
    u16* attn = (u16*)(ws + 75497472);       // 16,777,216
    u16* vtb  = (u16*)(ws + 92274688);       // 33,554,432  (total 125,829,120)

    // fused conversions: x, W_qkv, W_o
    cvt_all<<<6144, 256, 0, stream>>>(x, wqkv, wo, xb, wqb, wob);

    // QKV = x @ W_qkv^T  (M=8192, N=3072, K=1024)
    gemm_bt<u16><<<dim3(64, 24), 256, 0, stream>>>(xb, wqb, qkv, NB * NT, 3 * ND, ND);

    // V -> Vt[bh][d][t]
    transpose_v<<<dim3(64, 32), 256, 0, stream>>>(qkv, vtb);

    // attention (wave-pair-split flash, 64 keys/step)
    flash_prefix<<<dim3(64, 64), 256, 0, stream>>>(qkv, vtb, plen, attn);

    // out = attn @ W_o^T  (M=8192, N=1024, K=1024)
    gemm_bt<float><<<dim3(64, 8), 256, 0, stream>>>(attn, wob, out, NB * NT, ND, ND);
}

// Round 7
// 305.489 us; speedup vs baseline: 1.0092x; 1.0092x over previous
//
#include <hip/hip_runtime.h>
#include <stdint.h>

#define NB 4
#define NT 2048
#define ND 1024
#define NH 16
#define NDK 64
#define NTD 3072   // 3*ND

typedef __attribute__((ext_vector_type(8))) short short8;
typedef __attribute__((ext_vector_type(4))) float f32x4;
typedef unsigned short u16;
typedef unsigned int u32;

__device__ __forceinline__ u16 f2bf(float f) {
    u32 u = __builtin_bit_cast(u32, f);
    u += 0x7fffu + ((u >> 16) & 1u);   // RNE
    return (u16)(u >> 16);
}
__device__ __forceinline__ float bf2f(u16 s) {
    u32 u = ((u32)s) << 16;
    return __builtin_bit_cast(float, u);
}

__device__ __forceinline__ void gl_lds16(const u16* g, u16* l) {
    __builtin_amdgcn_global_load_lds(
        (const __attribute__((address_space(1))) u32*)g,
        (__attribute__((address_space(3))) u32*)l, 16, 0, 0);
}

// XOR-swizzled tile index (rows of 32 u16 / 64B, 4 atoms of 8 u16).
__device__ __forceinline__ int swz(int row, int col) {
    return row * 32 + ((((col >> 3) ^ (row >> 1) ^ (row >> 3)) & 3) << 3) + (col & 7);
}

// ---------------- fused fp32 -> bf16 (RNE) for x, W_qkv, W_o ----------------
__global__ __launch_bounds__(256) void cvt_all(const float* __restrict__ x,
                                               const float* __restrict__ wqkv,
                                               const float* __restrict__ wo,
                                               u16* __restrict__ xb,
                                               u16* __restrict__ wqb,
                                               u16* __restrict__ wob) {
    const int n0 = NB * NT * ND;       // 8388608
    const int n1 = 3 * ND * ND;        // 3145728
    int i = (blockIdx.x * 256 + threadIdx.x) * 8;
    const float* src;
    u16* dst;
    if (i < n0) {
        src = x + i; dst = xb + i;
    } else if (i < n0 + n1) {
        src = wqkv + (i - n0); dst = wqb + (i - n0);
    } else {
        src = wo + (i - n0 - n1); dst = wob + (i - n0 - n1);
    }
    float4 a = *(const float4*)(src);
    float4 b = *(const float4*)(src + 4);
    short8 r;
    r[0] = (short)f2bf(a.x); r[1] = (short)f2bf(a.y);
    r[2] = (short)f2bf(a.z); r[3] = (short)f2bf(a.w);
    r[4] = (short)f2bf(b.x); r[5] = (short)f2bf(b.y);
    r[6] = (short)f2bf(b.z); r[7] = (short)f2bf(b.w);
    *(short8*)(dst) = r;
}

// ---------------- bf16 GEMM: C[M,N] = A[M,K] * Bm[N,K]^T ----------------
template <typename OutT>
__global__ __launch_bounds__(256) void gemm_bt(const u16* __restrict__ A,
                                               const u16* __restrict__ Bm,
                                               OutT* __restrict__ C,
                                               int M, int N, int K) {
    __shared__ __align__(16) u16 As[128 * 32];
    __shared__ __align__(16) u16 Bs[128 * 32];
    const int tid  = threadIdx.x;
    const int wave = tid >> 6, lane = tid & 63;
    const int quad = lane >> 4, l16 = lane & 15;
    const int wm = wave >> 1, wn = wave & 1;
    const int row0 = blockIdx.x * 128, col0 = blockIdx.y * 128;

    f32x4 acc[4][4];
#pragma unroll
    for (int i = 0; i < 4; ++i)
#pragma unroll
        for (int j = 0; j < 4; ++j) acc[i][j] = (f32x4){0.f, 0.f, 0.f, 0.f};

    const u16* Ag = A + (size_t)(row0 + (tid >> 2)) * K + ((tid & 3) * 8);
    const u16* Bg = Bm + (size_t)(col0 + (tid >> 2)) * K + ((tid & 3) * 8);
    const size_t stride64 = (size_t)64 * K;
    u16* As0 = As + wave * 512;
    u16* As1 = As + 2048 + wave * 512;
    u16* Bs0 = Bs + wave * 512;
    u16* Bs1 = Bs + 2048 + wave * 512;

    for (int k0 = 0; k0 < K; k0 += 32) {
        gl_lds16(Ag + k0, As0);
        gl_lds16(Ag + k0 + stride64, As1);
        gl_lds16(Bg + k0, Bs0);
        gl_lds16(Bg + k0 + stride64, Bs1);
        __syncthreads();
        short8 af[4], bfr[4];
#pragma unroll
        for (int mi = 0; mi < 4; ++mi)
            af[mi] = *(const short8*)&As[(wm * 64 + mi * 16 + l16) * 32 + quad * 8];
#pragma unroll
        for (int ni = 0; ni < 4; ++ni)
            bfr[ni] = *(const short8*)&Bs[(wn * 64 + ni * 16 + l16) * 32 + quad * 8];
#pragma unroll
        for (int mi = 0; mi < 4; ++mi)
#pragma unroll
            for (int ni = 0; ni < 4; ++ni)
                acc[mi][ni] = __builtin_amdgcn_mfma_f32_16x16x32_bf16(
                    af[mi], bfr[ni], acc[mi][ni], 0, 0, 0);
        __syncthreads();
    }

#pragma unroll
    for (int mi = 0; mi < 4; ++mi) {
#pragma unroll
        for (int ni = 0; ni < 4; ++ni) {
            const int r = row0 + wm * 64 + mi * 16 + quad * 4;
            const int c = col0 + wn * 64 + ni * 16 + l16;
#pragma unroll
            for (int rr = 0; rr < 4; ++rr) {
                float v = acc[mi][ni][rr];
                if constexpr (sizeof(OutT) == 2)
                    C[(size_t)(r + rr) * N + c] = (OutT)f2bf(v);
                else
                    C[(size_t)(r + rr) * N + c] = (OutT)v;
            }
        }
    }
}

// ---------------- QKV GEMM with fused V-transpose epilogue ----------------
// Q,K column blocks (col0 < 2048) -> qkv row-major. V blocks -> vtb[bh][d][t]
// via per-wave 64x64 LDS transpose (phased through As/Bs).
__global__ __launch_bounds__(256) void gemm_qkv(const u16* __restrict__ A,
                                                const u16* __restrict__ Bm,
                                                u16* __restrict__ Cq,
                                                u16* __restrict__ vtb) {
    const int Kd = ND, Nn = NTD;
    __shared__ __align__(16) u16 As[128 * 32];
    __shared__ __align__(16) u16 Bs[128 * 32];
    const int tid  = threadIdx.x;
    const int wave = tid >> 6, lane = tid & 63;
    const int quad = lane >> 4, l16 = lane & 15;
    const int wm = wave >> 1, wn = wave & 1;
    const int row0 = blockIdx.x * 128, col0 = blockIdx.y * 128;

    f32x4 acc[4][4];
#pragma unroll
    for (int i = 0; i < 4; ++i)
#pragma unroll
        for (int j = 0; j < 4; ++j) acc[i][j] = (f32x4){0.f, 0.f, 0.f, 0.f};

    const u16* Ag = A + (size_t)(row0 + (tid >> 2)) * Kd + ((tid & 3) * 8);
    const u16* Bg = Bm + (size_t)(col0 + (tid >> 2)) * Kd + ((tid & 3) * 8);
    const size_t stride64 = (size_t)64 * Kd;
    u16* As0 = As + wave * 512;
    u16* As1 = As + 2048 + wave * 512;
    u16* Bs0 = Bs + wave * 512;
    u16* Bs1 = Bs + 2048 + wave * 512;

    for (int k0 = 0; k0 < Kd; k0 += 32) {
        gl_lds16(Ag + k0, As0);
        gl_lds16(Ag + k0 + stride64, As1);
        gl_lds16(Bg + k0, Bs0);
        gl_lds16(Bg + k0 + stride64, Bs1);
        __syncthreads();
        short8 af[4], bfr[4];
#pragma unroll
        for (int mi = 0; mi < 4; ++mi)
            af[mi] = *(const short8*)&As[(wm * 64 + mi * 16 + l16) * 32 + quad * 8];
#pragma unroll
        for (int ni = 0; ni < 4; ++ni)
            bfr[ni] = *(const short8*)&Bs[(wn * 64 + ni * 16 + l16) * 32 + quad * 8];
#pragma unroll
        for (int mi = 0; mi < 4; ++mi)
#pragma unroll
            for (int ni = 0; ni < 4; ++ni)
                acc[mi][ni] = __builtin_amdgcn_mfma_f32_16x16x32_bf16(
                    af[mi], bfr[ni], acc[mi][ni], 0, 0, 0);
        __syncthreads();
    }

    if (col0 < 2048) {
        // Q,K: row-major into qkv
#pragma unroll
        for (int mi = 0; mi < 4; ++mi)
#pragma unroll
            for (int ni = 0; ni < 4; ++ni) {
                const int r = row0 + wm * 64 + mi * 16 + quad * 4;
                const int c = col0 + wn * 64 + ni * 16 + l16;
#pragma unroll
                for (int rr = 0; rr < 4; ++rr)
                    Cq[(size_t)(r + rr) * Nn + c] = f2bf(acc[mi][ni][rr]);
            }
    } else {
        // V: transpose 64x64 per wave -> vtb[bh][d][t]
        const int hb = ((col0 - 2048) >> 6) + wn;         // head index 0..15
        const int bq = (row0 + wm * 64) >> 11;            // batch
        const int tb = (row0 + wm * 64) & 2047;           // t base
        u16* Ovt = vtb + (size_t)(bq * NH + hb) * 64 * NT + tb;
#pragma unroll
        for (int phase = 0; phase < 2; ++phase) {
            __syncthreads();
            if ((wave >> 1) == phase) {
                u16* L = (wave & 1) ? Bs : As;   // 4096 u16 = 64x64
#pragma unroll
                for (int mi = 0; mi < 4; ++mi) {
                    const int r4 = mi * 4 + quad;         // 4-elem r chunk idx
#pragma unroll
                    for (int ni = 0; ni < 4; ++ni) {
                        const int cl = ni * 16 + l16;     // local d
                        u32 lo = (u32)f2bf(acc[mi][ni][0]) | ((u32)f2bf(acc[mi][ni][1]) << 16);
                        u32 hi = (u32)f2bf(acc[mi][ni][2]) | ((u32)f2bf(acc[mi][ni][3]) << 16);
                        u32* p = (u32*)&L[cl * 64 + (((r4 ^ cl) & 15) << 2)];
                        p[0] = lo; p[1] = hi;
                    }
                }
#pragma unroll
                for (int rep = 0; rep < 8; ++rep) {
                    const int cl = (lane >> 3) + rep * 8; // local d row
                    const int tc = lane & 7;              // t chunk (8 u16)
                    const u32* p0 = (const u32*)&L[cl * 64 + ((((2 * tc) ^ cl) & 15) << 2)];
                    const u32* p1 = (const u32*)&L[cl * 64 + ((((2 * tc + 1) ^ cl) & 15) << 2)];
                    u32 o0 = p0[0], o1 = p0[1], o2 = p1[0], o3 = p1[1];
                    u32* q = (u32*)(Ovt + (size_t)cl * NT + tc * 8);
                    q[0] = o0; q[1] = o1; q[2] = o2; q[3] = o3;
                }
            }
        }
    }
}

// ---------------- flash prefix-LM attention (v7 = v5 inner + task queue) ----
// 1024 resident blocks pull (bh, q-tile) tasks LPT-ordered (longest first)
// from a global atomic counter. v5 inner loop: 64-row q-tiles, 4 waves x 16
// rows, 32-key steps, K/V DMA double-buffered, one barrier/step, constant-max
// exp2 softmax, ones-MFMA row sums.
__global__ __launch_bounds__(256) void flash_prefix(const u16* __restrict__ qkv,
                                                    const u16* __restrict__ vt,
                                                    const int* __restrict__ plen,
                                                    u16* __restrict__ attn,
                                                    u32* __restrict__ ctr) {
    __shared__ __align__(16) u16 Vt2[2][2048];  // [d 64][t 32] swizzled
    __shared__ __align__(16) u16 Kt2[2][2048];  // [k 32][d 64] swizzled
    __shared__ __align__(16) u16 Pl[4 * 512];   // per-wave 16x32 swizzled
    __shared__ int taskS;

    const int tid  = threadIdx.x;
    const int wave = tid >> 6, lane = tid & 63;
    const int quad = lane >> 4, l16 = lane & 15;
    const float QSCALE = 0.18033688f;           // log2(e)/8
    const int ldsoff = wave * 512;

    short8 ones;
#pragma unroll
    for (int j = 0; j < 8; ++j) ones[j] = (short)0x3F80;

    const bool is64 = (plen[1] == 0) && (plen[3] == 0);

    for (;;) {
        if (tid == 0) taskS = (int)atomicAdd(ctr, 1u);
        __syncthreads();            // broadcast + prev-task LDS reads done
        const int task = taskS;
        if (task >= 2048) break;

        const int bh = task & 63, b = bh >> 4, h = bh & 15;
        const int q0 = (31 - (task >> 6)) * 64;   // longest tiles first

        int P = is64 ? plen[2 * b] : plen[b];
        P = P < 0 ? 0 : (P > NT ? NT : P);

        const u16* Qg = qkv + (size_t)b * NT * NTD + h * NDK;
        const u16* Kg = Qg + ND;
        const u16* Vtb = vt + (size_t)bh * 64 * NT;   // [d][t]
        const int qbase = q0 + wave * 16;
        u16* Pw = Pl + wave * 512;

        // DMA lane->source mapping (swizzle baked into global address)
        const int vrow = tid >> 2;
        const int vtq = (tid ^ (vrow >> 1) ^ (vrow >> 3)) & 3;
        const u16* vsrc = Vtb + (size_t)vrow * NT + vtq * 8;
        const int krow = tid >> 3;
        const int kc = (tid ^ krow) & 7;
        const u16* ksrc = Kg + (size_t)krow * NTD + kc * 8;

        // Q fragments pre-scaled into exp2 domain
        short8 qa[2];
#pragma unroll
        for (int kd = 0; kd < 2; ++kd) {
            short8 tq = *(const short8*)(Qg + (size_t)(qbase + l16) * NTD + kd * 32 + quad * 8);
#pragma unroll
            for (int j = 0; j < 8; ++j)
                tq[j] = (short)f2bf(bf2f((u16)tq[j]) * QSCALE);
            qa[kd] = tq;
        }

        f32x4 o[4];
#pragma unroll
        for (int nt = 0; nt < 4; ++nt) o[nt] = (f32x4){0.f, 0.f, 0.f, 0.f};
        f32x4 lsum = (f32x4){0.f, 0.f, 0.f, 0.f};

        int kl[4];
#pragma unroll
        for (int rr = 0; rr < 4; ++rr) {
            const int qrow = qbase + quad * 4 + rr;
            kl[rr] = (qrow < P) ? P : (qrow + 1);
        }
        const int klmin = (qbase < P) ? P : (qbase + 1);  // wave-uniform
        const int kmax = (q0 + 64 > P) ? (q0 + 64) : P;   // block-uniform

        gl_lds16(vsrc, &Vt2[0][ldsoff]);
        gl_lds16(ksrc, &Kt2[0][ldsoff]);
        int buf = 0;

        for (int k0 = 0; k0 < kmax; k0 += 32) {
            __syncthreads();
            if (k0 + 32 < kmax) {
                gl_lds16(vsrc + (k0 + 32), &Vt2[buf ^ 1][ldsoff]);
                gl_lds16(ksrc + (size_t)(k0 + 32) * NTD, &Kt2[buf ^ 1][ldsoff]);
            }
            const u16* Kb = Kt2[buf];
            const u16* Vb = Vt2[buf];

            f32x4 s[2];
#pragma unroll
            for (int ni = 0; ni < 2; ++ni) {
                s[ni] = (f32x4){0.f, 0.f, 0.f, 0.f};
#pragma unroll
                for (int kd = 0; kd < 2; ++kd) {
                    const int r = ni * 16 + l16;
                    const short8 kb = *(const short8*)&Kb[r * 64 + ((((kd * 4 + quad) ^ r) & 7) << 3)];
                    s[ni] = __builtin_amdgcn_mfma_f32_16x16x32_bf16(qa[kd], kb, s[ni], 0, 0, 0);
                }
            }

            const bool full = (k0 + 32 <= klmin);
#pragma unroll
            for (int ni = 0; ni < 2; ++ni) {
#pragma unroll
                for (int rr = 0; rr < 4; ++rr) {
                    float sv = s[ni][rr];
                    if (!full) {
                        const int kpos = k0 + ni * 16 + l16;
                        sv = (kpos < kl[rr]) ? sv : -1e30f;
                    }
                    const float p = exp2f(sv);
                    const u32 u = __builtin_bit_cast(u32, p) + 0x8000u;
                    Pw[swz(quad * 4 + rr, ni * 16 + l16)] = (u16)(u >> 16);
                }
            }

            const short8 pa = *(const short8*)&Pw[swz(l16, quad * 8)];
            lsum = __builtin_amdgcn_mfma_f32_16x16x32_bf16(pa, ones, lsum, 0, 0, 0);
#pragma unroll
            for (int nt = 0; nt < 4; ++nt) {
                const short8 vb = *(const short8*)&Vb[swz(nt * 16 + l16, quad * 8)];
                o[nt] = __builtin_amdgcn_mfma_f32_16x16x32_bf16(pa, vb, o[nt], 0, 0, 0);
            }
            buf ^= 1;
        }

        // epilogue (no shuffles: lsum shares o's C-layout)
#pragma unroll
        for (int rr = 0; rr < 4; ++rr) {
            const float inv = 1.0f / lsum[rr];
            const size_t rowoff = (size_t)(b * NT + qbase + quad * 4 + rr) * ND + h * NDK;
#pragma unroll
            for (int nt = 0; nt < 4; ++nt)
                attn[rowoff + nt * 16 + l16] = f2bf(o[nt][rr] * inv);
        }
    }
}

extern "C" void kernel_launch(void* const* d_in, const int* in_sizes, int n_in,
                              void* d_out, int out_size, void* d_ws, size_t ws_size,
                              hipStream_t stream) {
    const float* x    = (const float*)d_in[0];
    const int*   plen = (const int*)d_in[1];
    const float* wqkv = (const float*)d_in[2];
    const float* wo   = (const float*)d_in[3];
    float* out = (float*)d_out;

    char* ws = (char*)d_ws;
    u16* xb   = (u16*)(ws);                  // 16,777,216
    u16* wqb  = (u16*)(ws + 16777216);       //  6,291,456
    u16* wob  = (u16*)(ws + 23068672);       //  2,097,152
    u16* qkv  = (u16*)(ws + 25165824);       // 50,331,648 (V cols unused)
    u16* attn = (u16*)(ws + 75497472);       // 16,777,216
    u16* vtb  = (u16*)(ws + 92274688);       // 33,554,432
    u32* ctr  = (u32*)(ws + 75497468);       // last 4B of qkv V-section (unused)

    hipMemsetAsync(ctr, 0, 4, stream);

    // fused conversions: x, W_qkv, W_o
    cvt_all<<<6144, 256, 0, stream>>>(x, wqkv, wo, xb, wqb, wob);

    // QKV GEMM; V columns go directly to vtb[bh][d][t]
    gemm_qkv<<<dim3(64, 24), 256, 0, stream>>>(xb, wqb, qkv, vtb);

    // attention (task-queue flash, LPT order)
    flash_prefix<<<1024, 256, 0, stream>>>(qkv, vtb, plen, attn, ctr);

    // out = attn @ W_o^T  (M=8192, N=1024, K=1024)
    gemm_bt<float><<<dim3(64, 8), 256, 0, stream>>>(attn, wob, out, NB * NT, ND, ND);
}

// Round 8
// 298.816 us; speedup vs baseline: 1.0317x; 1.0223x over previous
//
#include <hip/hip_runtime.h>
#include <stdint.h>

#define NB 4
#define NT 2048
#define ND 1024
#define NH 16
#define NDK 64
#define NTD 3072   // 3*ND

typedef __attribute__((ext_vector_type(8))) short short8;
typedef __attribute__((ext_vector_type(4))) float f32x4;
typedef unsigned short u16;
typedef unsigned int u32;

__device__ __forceinline__ u16 f2bf(float f) {
    u32 u = __builtin_bit_cast(u32, f);
    u += 0x7fffu + ((u >> 16) & 1u);   // RNE
    return (u16)(u >> 16);
}
__device__ __forceinline__ float bf2f(u16 s) {
    u32 u = ((u32)s) << 16;
    return __builtin_bit_cast(float, u);
}

__device__ __forceinline__ void gl_lds16(const u16* g, u16* l) {
    __builtin_amdgcn_global_load_lds(
        (const __attribute__((address_space(1))) u32*)g,
        (__attribute__((address_space(3))) u32*)l, 16, 0, 0);
}

// XOR-swizzled tile index (rows of 32 u16 / 64B, 4 atoms of 8 u16).
__device__ __forceinline__ int swz(int row, int col) {
    return row * 32 + ((((col >> 3) ^ (row >> 1) ^ (row >> 3)) & 3) << 3) + (col & 7);
}

// ---------------- fused fp32 -> bf16 (RNE) for x, W_qkv, W_o ----------------
__global__ __launch_bounds__(256) void cvt_all(const float* __restrict__ x,
                                               const float* __restrict__ wqkv,
                                               const float* __restrict__ wo,
                                               u16* __restrict__ xb,
                                               u16* __restrict__ wqb,
                                               u16* __restrict__ wob) {
    const int n0 = NB * NT * ND;       // 8388608
    const int n1 = 3 * ND * ND;        // 3145728
    int i = (blockIdx.x * 256 + threadIdx.x) * 8;
    const float* src;
    u16* dst;
    if (i < n0) {
        src = x + i; dst = xb + i;
    } else if (i < n0 + n1) {
        src = wqkv + (i - n0); dst = wqb + (i - n0);
    } else {
        src = wo + (i - n0 - n1); dst = wob + (i - n0 - n1);
    }
    float4 a = *(const float4*)(src);
    float4 b = *(const float4*)(src + 4);
    short8 r;
    r[0] = (short)f2bf(a.x); r[1] = (short)f2bf(a.y);
    r[2] = (short)f2bf(a.z); r[3] = (short)f2bf(a.w);
    r[4] = (short)f2bf(b.x); r[5] = (short)f2bf(b.y);
    r[6] = (short)f2bf(b.z); r[7] = (short)f2bf(b.w);
    *(short8*)(dst) = r;
}

// ---------------- bf16 GEMM: C[M,N] = A[M,K] * Bm[N,K]^T ----------------
template <typename OutT>
__global__ __launch_bounds__(256) void gemm_bt(const u16* __restrict__ A,
                                               const u16* __restrict__ Bm,
                                               OutT* __restrict__ C,
                                               int M, int N, int K) {
    __shared__ __align__(16) u16 As[128 * 32];
    __shared__ __align__(16) u16 Bs[128 * 32];
    const int tid  = threadIdx.x;
    const int wave = tid >> 6, lane = tid & 63;
    const int quad = lane >> 4, l16 = lane & 15;
    const int wm = wave >> 1, wn = wave & 1;
    const int row0 = blockIdx.x * 128, col0 = blockIdx.y * 128;

    f32x4 acc[4][4];
#pragma unroll
    for (int i = 0; i < 4; ++i)
#pragma unroll
        for (int j = 0; j < 4; ++j) acc[i][j] = (f32x4){0.f, 0.f, 0.f, 0.f};

    const u16* Ag = A + (size_t)(row0 + (tid >> 2)) * K + ((tid & 3) * 8);
    const u16* Bg = Bm + (size_t)(col0 + (tid >> 2)) * K + ((tid & 3) * 8);
    const size_t stride64 = (size_t)64 * K;
    u16* As0 = As + wave * 512;
    u16* As1 = As + 2048 + wave * 512;
    u16* Bs0 = Bs + wave * 512;
    u16* Bs1 = Bs + 2048 + wave * 512;

    for (int k0 = 0; k0 < K; k0 += 32) {
        gl_lds16(Ag + k0, As0);
        gl_lds16(Ag + k0 + stride64, As1);
        gl_lds16(Bg + k0, Bs0);
        gl_lds16(Bg + k0 + stride64, Bs1);
        __syncthreads();
        short8 af[4], bfr[4];
#pragma unroll
        for (int mi = 0; mi < 4; ++mi)
            af[mi] = *(const short8*)&As[(wm * 64 + mi * 16 + l16) * 32 + quad * 8];
#pragma unroll
        for (int ni = 0; ni < 4; ++ni)
            bfr[ni] = *(const short8*)&Bs[(wn * 64 + ni * 16 + l16) * 32 + quad * 8];
#pragma unroll
        for (int mi = 0; mi < 4; ++mi)
#pragma unroll
            for (int ni = 0; ni < 4; ++ni)
                acc[mi][ni] = __builtin_amdgcn_mfma_f32_16x16x32_bf16(
                    af[mi], bfr[ni], acc[mi][ni], 0, 0, 0);
        __syncthreads();
    }

#pragma unroll
    for (int mi = 0; mi < 4; ++mi) {
#pragma unroll
        for (int ni = 0; ni < 4; ++ni) {
            const int r = row0 + wm * 64 + mi * 16 + quad * 4;
            const int c = col0 + wn * 64 + ni * 16 + l16;
#pragma unroll
            for (int rr = 0; rr < 4; ++rr) {
                float v = acc[mi][ni][rr];
                if constexpr (sizeof(OutT) == 2)
                    C[(size_t)(r + rr) * N + c] = (OutT)f2bf(v);
                else
                    C[(size_t)(r + rr) * N + c] = (OutT)v;
            }
        }
    }
}

// ---------------- QKV GEMM with fused V-transpose epilogue ----------------
__global__ __launch_bounds__(256) void gemm_qkv(const u16* __restrict__ A,
                                                const u16* __restrict__ Bm,
                                                u16* __restrict__ Cq,
                                                u16* __restrict__ vtb) {
    const int Kd = ND, Nn = NTD;
    __shared__ __align__(16) u16 As[128 * 32];
    __shared__ __align__(16) u16 Bs[128 * 32];
    const int tid  = threadIdx.x;
    const int wave = tid >> 6, lane = tid & 63;
    const int quad = lane >> 4, l16 = lane & 15;
    const int wm = wave >> 1, wn = wave & 1;
    const int row0 = blockIdx.x * 128, col0 = blockIdx.y * 128;

    f32x4 acc[4][4];
#pragma unroll
    for (int i = 0; i < 4; ++i)
#pragma unroll
        for (int j = 0; j < 4; ++j) acc[i][j] = (f32x4){0.f, 0.f, 0.f, 0.f};

    const u16* Ag = A + (size_t)(row0 + (tid >> 2)) * Kd + ((tid & 3) * 8);
    const u16* Bg = Bm + (size_t)(col0 + (tid >> 2)) * Kd + ((tid & 3) * 8);
    const size_t stride64 = (size_t)64 * Kd;
    u16* As0 = As + wave * 512;
    u16* As1 = As + 2048 + wave * 512;
    u16* Bs0 = Bs + wave * 512;
    u16* Bs1 = Bs + 2048 + wave * 512;

    for (int k0 = 0; k0 < Kd; k0 += 32) {
        gl_lds16(Ag + k0, As0);
        gl_lds16(Ag + k0 + stride64, As1);
        gl_lds16(Bg + k0, Bs0);
        gl_lds16(Bg + k0 + stride64, Bs1);
        __syncthreads();
        short8 af[4], bfr[4];
#pragma unroll
        for (int mi = 0; mi < 4; ++mi)
            af[mi] = *(const short8*)&As[(wm * 64 + mi * 16 + l16) * 32 + quad * 8];
#pragma unroll
        for (int ni = 0; ni < 4; ++ni)
            bfr[ni] = *(const short8*)&Bs[(wn * 64 + ni * 16 + l16) * 32 + quad * 8];
#pragma unroll
        for (int mi = 0; mi < 4; ++mi)
#pragma unroll
            for (int ni = 0; ni < 4; ++ni)
                acc[mi][ni] = __builtin_amdgcn_mfma_f32_16x16x32_bf16(
                    af[mi], bfr[ni], acc[mi][ni], 0, 0, 0);
        __syncthreads();
    }

    if (col0 < 2048) {
        // Q,K: row-major into qkv
#pragma unroll
        for (int mi = 0; mi < 4; ++mi)
#pragma unroll
            for (int ni = 0; ni < 4; ++ni) {
                const int r = row0 + wm * 64 + mi * 16 + quad * 4;
                const int c = col0 + wn * 64 + ni * 16 + l16;
#pragma unroll
                for (int rr = 0; rr < 4; ++rr)
                    Cq[(size_t)(r + rr) * Nn + c] = f2bf(acc[mi][ni][rr]);
            }
    } else {
        // V: transpose 64x64 per wave -> vtb[bh][d][t]
        const int hb = ((col0 - 2048) >> 6) + wn;         // head index 0..15
        const int bq = (row0 + wm * 64) >> 11;            // batch
        const int tb = (row0 + wm * 64) & 2047;           // t base
        u16* Ovt = vtb + (size_t)(bq * NH + hb) * 64 * NT + tb;
#pragma unroll
        for (int phase = 0; phase < 2; ++phase) {
            __syncthreads();
            if ((wave >> 1) == phase) {
                u16* L = (wave & 1) ? Bs : As;   // 4096 u16 = 64x64
#pragma unroll
                for (int mi = 0; mi < 4; ++mi) {
                    const int r4 = mi * 4 + quad;         // 4-elem r chunk idx
#pragma unroll
                    for (int ni = 0; ni < 4; ++ni) {
                        const int cl = ni * 16 + l16;     // local d
                        u32 lo = (u32)f2bf(acc[mi][ni][0]) | ((u32)f2bf(acc[mi][ni][1]) << 16);
                        u32 hi = (u32)f2bf(acc[mi][ni][2]) | ((u32)f2bf(acc[mi][ni][3]) << 16);
                        u32* p = (u32*)&L[cl * 64 + (((r4 ^ cl) & 15) << 2)];
                        p[0] = lo; p[1] = hi;
                    }
                }
#pragma unroll
                for (int rep = 0; rep < 8; ++rep) {
                    const int cl = (lane >> 3) + rep * 8; // local d row
                    const int tc = lane & 7;              // t chunk (8 u16)
                    const u32* p0 = (const u32*)&L[cl * 64 + ((((2 * tc) ^ cl) & 15) << 2)];
                    const u32* p1 = (const u32*)&L[cl * 64 + ((((2 * tc + 1) ^ cl) & 15) << 2)];
                    u32 o0 = p0[0], o1 = p0[1], o2 = p1[0], o3 = p1[1];
                    u32* q = (u32*)(Ovt + (size_t)cl * NT + tc * 8);
                    q[0] = o0; q[1] = o1; q[2] = o2; q[3] = o3;
                }
            }
        }
    }
}

// ---------------- flash prefix-LM attention (v8) ----------------
// v5 inner loop + XCD-local LPT task queues. Queue x: 256 tasks =
// 8 bh (= [8x,8x+8), all same batch b hence same P) x 32 q-tiles,
// longest-tile-first. Blocks drain own XCD's queue (L2 locality:
// 8 bh x 0.5 MB = 4 MB = one XCD L2), then steal for correctness.
#define GETREG_XCC_ID 6164   // id=20, offset=0, size=4
__global__ __launch_bounds__(256) void flash_prefix(const u16* __restrict__ qkv,
                                                    const u16* __restrict__ vt,
                                                    const int* __restrict__ plen,
                                                    u16* __restrict__ attn,
                                                    u32* __restrict__ ctr) {
    __shared__ __align__(16) u16 Vt2[2][2048];  // [d 64][t 32] swizzled
    __shared__ __align__(16) u16 Kt2[2][2048];  // [k 32][d 64] swizzled
    __shared__ __align__(16) u16 Pl[4 * 512];   // per-wave 16x32 swizzled
    __shared__ int taskS;

    const int tid  = threadIdx.x;
    const int wave = tid >> 6, lane = tid & 63;
    const int quad = lane >> 4, l16 = lane & 15;
    const float QSCALE = 0.18033688f;           // log2(e)/8
    const int ldsoff = wave * 512;

    short8 ones;
#pragma unroll
    for (int j = 0; j < 8; ++j) ones[j] = (short)0x3F80;

    const bool is64 = (plen[1] == 0) && (plen[3] == 0);
    const int xcd = (int)(__builtin_amdgcn_s_getreg(GETREG_XCC_ID) & 7);
    int q = xcd;

    for (;;) {
        if (tid == 0) taskS = (int)atomicAdd(ctr + q * 16, 1u);
        __syncthreads();            // broadcast + prev-task LDS reads done
        const int pos = taskS;
        if (pos >= 256) {           // queue q drained; steal or finish
            q = (q + 1) & 7;
            if (q == xcd) break;
            continue;
        }

        const int bh = (q << 3) | (pos & 7);
        const int b = bh >> 4, h = bh & 15;
        const int q0 = (31 - (pos >> 3)) * 64;   // LPT: longest tiles first

        int P = is64 ? plen[2 * b] : plen[b];
        P = P < 0 ? 0 : (P > NT ? NT : P);

        const u16* Qg = qkv + (size_t)b * NT * NTD + h * NDK;
        const u16* Kg = Qg + ND;
        const u16* Vtb = vt + (size_t)bh * 64 * NT;   // [d][t]
        const int qbase = q0 + wave * 16;
        u16* Pw = Pl + wave * 512;

        // DMA lane->source mapping (swizzle baked into global address)
        const int vrow = tid >> 2;
        const int vtq = (tid ^ (vrow >> 1) ^ (vrow >> 3)) & 3;
        const u16* vsrc = Vtb + (size_t)vrow * NT + vtq * 8;
        const int krow = tid >> 3;
        const int kc = (tid ^ krow) & 7;
        const u16* ksrc = Kg + (size_t)krow * NTD + kc * 8;

        // Q fragments pre-scaled into exp2 domain
        short8 qa[2];
#pragma unroll
        for (int kd = 0; kd < 2; ++kd) {
            short8 tq = *(const short8*)(Qg + (size_t)(qbase + l16) * NTD + kd * 32 + quad * 8);
#pragma unroll
            for (int j = 0; j < 8; ++j)
                tq[j] = (short)f2bf(bf2f((u16)tq[j]) * QSCALE);
            qa[kd] = tq;
        }

        f32x4 o[4];
#pragma unroll
        for (int nt = 0; nt < 4; ++nt) o[nt] = (f32x4){0.f, 0.f, 0.f, 0.f};
        f32x4 lsum = (f32x4){0.f, 0.f, 0.f, 0.f};

        int kl[4];
#pragma unroll
        for (int rr = 0; rr < 4; ++rr) {
            const int qrow = qbase + quad * 4 + rr;
            kl[rr] = (qrow < P) ? P : (qrow + 1);
        }
        const int klmin = (qbase < P) ? P : (qbase + 1);  // wave-uniform
        const int kmax = (q0 + 64 > P) ? (q0 + 64) : P;   // block-uniform

        gl_lds16(vsrc, &Vt2[0][ldsoff]);
        gl_lds16(ksrc, &Kt2[0][ldsoff]);
        int buf = 0;

        for (int k0 = 0; k0 < kmax; k0 += 32) {
            __syncthreads();
            if (k0 + 32 < kmax) {
                gl_lds16(vsrc + (k0 + 32), &Vt2[buf ^ 1][ldsoff]);
                gl_lds16(ksrc + (size_t)(k0 + 32) * NTD, &Kt2[buf ^ 1][ldsoff]);
            }
            const u16* Kb = Kt2[buf];
            const u16* Vb = Vt2[buf];

            f32x4 s[2];
#pragma unroll
            for (int ni = 0; ni < 2; ++ni) {
                s[ni] = (f32x4){0.f, 0.f, 0.f, 0.f};
#pragma unroll
                for (int kd = 0; kd < 2; ++kd) {
                    const int r = ni * 16 + l16;
                    const short8 kb = *(const short8*)&Kb[r * 64 + ((((kd * 4 + quad) ^ r) & 7) << 3)];
                    s[ni] = __builtin_amdgcn_mfma_f32_16x16x32_bf16(qa[kd], kb, s[ni], 0, 0, 0);
                }
            }

            const bool full = (k0 + 32 <= klmin);
#pragma unroll
            for (int ni = 0; ni < 2; ++ni) {
#pragma unroll
                for (int rr = 0; rr < 4; ++rr) {
                    float sv = s[ni][rr];
                    if (!full) {
                        const int kpos = k0 + ni * 16 + l16;
                        sv = (kpos < kl[rr]) ? sv : -1e30f;
                    }
                    const float p = exp2f(sv);
                    const u32 u = __builtin_bit_cast(u32, p) + 0x8000u;
                    Pw[swz(quad * 4 + rr, ni * 16 + l16)] = (u16)(u >> 16);
                }
            }

            const short8 pa = *(const short8*)&Pw[swz(l16, quad * 8)];
            lsum = __builtin_amdgcn_mfma_f32_16x16x32_bf16(pa, ones, lsum, 0, 0, 0);
#pragma unroll
            for (int nt = 0; nt < 4; ++nt) {
                const short8 vb = *(const short8*)&Vb[swz(nt * 16 + l16, quad * 8)];
                o[nt] = __builtin_amdgcn_mfma_f32_16x16x32_bf16(pa, vb, o[nt], 0, 0, 0);
            }
            buf ^= 1;
        }

        // epilogue (no shuffles: lsum shares o's C-layout)
#pragma unroll
        for (int rr = 0; rr < 4; ++rr) {
            const float inv = 1.0f / lsum[rr];
            const size_t rowoff = (size_t)(b * NT + qbase + quad * 4 + rr) * ND + h * NDK;
#pragma unroll
            for (int nt = 0; nt < 4; ++nt)
                attn[rowoff + nt * 16 + l16] = f2bf(o[nt][rr] * inv);
        }
    }
}

extern "C" void kernel_launch(void* const* d_in, const int* in_sizes, int n_in,
                              void* d_out, int out_size, void* d_ws, size_t ws_size,
                              hipStream_t stream) {
    const float* x    = (const float*)d_in[0];
    const int*   plen = (const int*)d_in[1];
    const float* wqkv = (const float*)d_in[2];
    const float* wo   = (const float*)d_in[3];
    float* out = (float*)d_out;

    char* ws = (char*)d_ws;
    u16* xb   = (u16*)(ws);                  // 16,777,216
    u16* wqb  = (u16*)(ws + 16777216);       //  6,291,456
    u16* wob  = (u16*)(ws + 23068672);       //  2,097,152
    u16* qkv  = (u16*)(ws + 25165824);       // 50,331,648 (V cols unused)
    u16* attn = (u16*)(ws + 75497472);       // 16,777,216
    u16* vtb  = (u16*)(ws + 92274688);       // 33,554,432
    u32* ctr  = (u32*)(ws + 75496960);       // 512 B inside unused qkv V-section

    hipMemsetAsync(ctr, 0, 512, stream);

    // fused conversions: x, W_qkv, W_o
    cvt_all<<<6144, 256, 0, stream>>>(x, wqkv, wo, xb, wqb, wob);

    // QKV GEMM; V columns go directly to vtb[bh][d][t]
    gemm_qkv<<<dim3(64, 24), 256, 0, stream>>>(xb, wqb, qkv, vtb);

    // attention (XCD-local LPT task queues)
    flash_prefix<<<1024, 256, 0, stream>>>(qkv, vtb, plen, attn, ctr);

    // out = attn @ W_o^T  (M=8192, N=1024, K=1024)
    gemm_bt<float><<<dim3(64, 8), 256, 0, stream>>>(attn, wob, out, NB * NT, ND, ND);
}